// Round 1
// baseline (368.478 us; speedup 1.0000x reference)
//
#include <hip/hip_runtime.h>

#define NN 4096
#define BHH 64

// ws layout (floats)
#define OFF_G  0
#define OFF_S  4096
#define OFF_T  (OFF_S + 64*4096)
#define OFF_GS (OFF_T + 64*4096)
#define OFF_PG (OFF_GS + 64*128*64)

// ---------------- Kernel A: G = P^T P  (P is [64,64]) ----------------
__global__ void kA_gram(const float* __restrict__ P, float* __restrict__ G) {
    int i = blockIdx.x;      // 0..63
    int j = threadIdx.x;     // 0..63
    float acc = 0.f;
    for (int m = 0; m < 64; ++m)
        acc += P[m*64 + i] * P[m*64 + j];
    G[i*64 + j] = acc;
}

// ------- Kernel B: per (head, 256-row chunk): S += K^T V, kg = K@G, group sums -------
__launch_bounds__(256)
__global__ void kB(const float* __restrict__ k, const float* __restrict__ v,
                   const float* __restrict__ G, float* __restrict__ kg_out,
                   float* __restrict__ S, float* __restrict__ gs) {
    __shared__ __align__(16) float Gs[64*64];
    __shared__ __align__(16) float kt[32*68];   // stride 17 float4 (pad breaks bank stride)
    __shared__ __align__(16) float vt[32*68];

    int t = threadIdx.x;
    int head = blockIdx.y, chunk = blockIdx.x;
    long base = ((long)head*NN + (long)chunk*256) * 64;

    float4*       Gs4 = (float4*)Gs;
    const float4* G4  = (const float4*)G;
#pragma unroll
    for (int i = 0; i < 4; ++i) Gs4[t + 256*i] = G4[t + 256*i];

    int dg = t >> 4, eg = t & 15;     // S tile: d=dg*4.., e=eg*4..
    int rg = t >> 4, cg = t & 15;     // kg tile: rows rg*2,+1 ; cols cg*4..
    float accS[4][4] = {};

    float4* kt4 = (float4*)kt;
    float4* vt4 = (float4*)vt;

    for (int s = 0; s < 8; ++s) {
        __syncthreads();  // protect kt/vt (and Gs on first iter)
        const float4* kgl = (const float4*)(k + base + (long)s*32*64);
        const float4* vgl = (const float4*)(v + base + (long)s*32*64);
#pragma unroll
        for (int i = 0; i < 2; ++i) {
            int f = t + 256*i;            // 0..511 : row=f>>4, colquad=f&15
            int r = f >> 4, c = f & 15;
            kt4[r*17 + c] = kgl[f];
            vt4[r*17 + c] = vgl[f];
        }
        __syncthreads();

        // ---- S accumulation: S[d][e] += k[r][d]*v[r][e] ----
#pragma unroll 4
        for (int r = 0; r < 32; ++r) {
            float4 kv = kt4[r*17 + dg];
            float4 vv = vt4[r*17 + eg];
            float ks[4] = {kv.x, kv.y, kv.z, kv.w};
            float vs[4] = {vv.x, vv.y, vv.z, vv.w};
#pragma unroll
            for (int i = 0; i < 4; ++i)
#pragma unroll
                for (int j = 0; j < 4; ++j)
                    accS[i][j] += ks[i]*vs[j];
        }

        // ---- kg GEMM: kg[r][c] = sum_kk k[r][kk]*G[kk][c] ----
        float a[2][4] = {};
#pragma unroll
        for (int kq = 0; kq < 16; ++kq) {
            float4 ga0 = Gs4[(kq*4+0)*16 + cg];
            float4 ga1 = Gs4[(kq*4+1)*16 + cg];
            float4 ga2 = Gs4[(kq*4+2)*16 + cg];
            float4 ga3 = Gs4[(kq*4+3)*16 + cg];
            float4 ka = kt4[(rg*2+0)*17 + kq];
            float4 kb = kt4[(rg*2+1)*17 + kq];
            float gg[4][4] = {{ga0.x,ga0.y,ga0.z,ga0.w},{ga1.x,ga1.y,ga1.z,ga1.w},
                              {ga2.x,ga2.y,ga2.z,ga2.w},{ga3.x,ga3.y,ga3.z,ga3.w}};
            float kaa[4] = {ka.x,ka.y,ka.z,ka.w};
            float kbb[4] = {kb.x,kb.y,kb.z,kb.w};
#pragma unroll
            for (int u = 0; u < 4; ++u)
#pragma unroll
                for (int j = 0; j < 4; ++j) {
                    a[0][j] += kaa[u]*gg[u][j];
                    a[1][j] += kbb[u]*gg[u][j];
                }
        }
        float4* kgo = (float4*)(kg_out + base + (long)s*32*64);
        kgo[(rg*2+0)*16 + cg] = make_float4(a[0][0],a[0][1],a[0][2],a[0][3]);
        kgo[(rg*2+1)*16 + cg] = make_float4(a[1][0],a[1][1],a[1][2],a[1][3]);

        // ---- 32-row group sums of raw k (for scan) ----
        if (t < 64) {
            float gsum = 0.f;
#pragma unroll 8
            for (int r = 0; r < 32; ++r) gsum += kt[r*68 + t];
            gs[((long)head*128 + chunk*8 + s)*64 + t] = gsum;
        }
    }

    // flush S
#pragma unroll
    for (int i = 0; i < 4; ++i)
#pragma unroll
        for (int j = 0; j < 4; ++j)
            atomicAdd(&S[head*4096 + (dg*4+i)*64 + (eg*4+j)], accS[i][j]);
}

// ------- Kernel C: per head: scan group sums -> prefixes@G ; T = G@S -------
__launch_bounds__(256)
__global__ void kC(const float* __restrict__ G, const float* __restrict__ S,
                   float* __restrict__ T, const float* __restrict__ gs,
                   float* __restrict__ pg) {
    __shared__ float Gsp[64*65];            // padded stride
    __shared__ __align__(16) float Ss[64*64];
    __shared__ float kpre[128*65];          // padded stride

    int t = threadIdx.x;
    int head = blockIdx.x;

    for (int idx = t; idx < 4096; idx += 256)
        Gsp[(idx>>6)*65 + (idx&63)] = G[idx];
    const float4* S4  = (const float4*)(S + head*4096);
    float4*       Ss4 = (float4*)Ss;
#pragma unroll
    for (int i = 0; i < 4; ++i) Ss4[t + 256*i] = S4[t + 256*i];

    if (t < 64) {   // exclusive scan over 128 groups
        float run = 0.f;
        for (int g = 0; g < 128; ++g) {
            float x = gs[((long)head*128 + g)*64 + t];
            kpre[g*65 + t] = run;
            run += x;
        }
    }
    __syncthreads();

    // T = G @ S
    {
        int ig = t >> 4, jg = t & 15;
        float acc[4][4] = {};
        for (int kk = 0; kk < 64; ++kk) {
            float4 sv = Ss4[kk*16 + jg];
            float svv[4] = {sv.x, sv.y, sv.z, sv.w};
            float gr[4];
#pragma unroll
            for (int i = 0; i < 4; ++i) gr[i] = Gsp[(ig*4+i)*65 + kk];
#pragma unroll
            for (int i = 0; i < 4; ++i)
#pragma unroll
                for (int j = 0; j < 4; ++j)
                    acc[i][j] += gr[i]*svv[j];
        }
        float4* T4 = (float4*)(T + head*4096);
#pragma unroll
        for (int i = 0; i < 4; ++i)
            T4[(ig*4+i)*16 + jg] = make_float4(acc[i][0],acc[i][1],acc[i][2],acc[i][3]);
    }

    // pg = kpre @ G   (kg-space prefixes)
    {
        int g0 = (t >> 4) * 8, c0 = (t & 15) * 4;
        float acc[8][4] = {};
        for (int d = 0; d < 64; ++d) {
            float gr[4];
#pragma unroll
            for (int j = 0; j < 4; ++j) gr[j] = Gsp[d*65 + c0 + j];
#pragma unroll
            for (int i = 0; i < 8; ++i) {
                float kv = kpre[(g0+i)*65 + d];
#pragma unroll
                for (int j = 0; j < 4; ++j) acc[i][j] += kv*gr[j];
            }
        }
        float4* pg4 = (float4*)(pg + (long)head*128*64);
#pragma unroll
        for (int i = 0; i < 8; ++i)
            pg4[(g0+i)*16 + (t&15)] = make_float4(acc[i][0],acc[i][1],acc[i][2],acc[i][3]);
    }
}

// ------- Kernel D: denominators (cumsum of kg) + out = (Q@T) * 1/denom -------
__launch_bounds__(256)
__global__ void kD(const float* __restrict__ q, const float* __restrict__ kg,
                   const float* __restrict__ T, const float* __restrict__ pg,
                   float* __restrict__ out) {
    __shared__ __align__(16) float Ts[64*64];
    __shared__ float qs[4][32*65];
    __shared__ float dinvs[4][32];

    int t = threadIdx.x;
    int w = t >> 6, lane = t & 63;
    int head = blockIdx.y, tile = blockIdx.x;  // tile 0..31
    int g = tile*4 + w;                        // 32-row group 0..127
    long rowbase = (long)head*NN + (long)g*32;

    const float4* T4  = (const float4*)(T + head*4096);
    float4*       Ts4 = (float4*)Ts;
#pragma unroll
    for (int i = 0; i < 4; ++i) Ts4[t + 256*i] = T4[t + 256*i];

    // ---- phase A: lane-register cumsum + denominators ----
    float ckg = pg[((long)head*128 + g)*64 + lane];
#pragma unroll 4
    for (int r = 0; r < 32; ++r) {
        long off = (rowbase + r)*64 + lane;
        float qv  = q[off];
        float kgv = kg[off];
        ckg += kgv;
        float p = qv * ckg;
#pragma unroll
        for (int o = 32; o; o >>= 1) p += __shfl_xor(p, o, 64);
        qs[w][r*65 + lane] = qv;
        if (lane == 0) dinvs[w][r] = __builtin_amdgcn_rcpf(p);
    }
    __syncthreads();

    // ---- phase B: OUT[32][64] = Q[32][64] @ T[64][64], scaled ----
    int rg = lane >> 3, cg = lane & 7;   // rows rg*4.., cols cg*8..
    float acc[4][8] = {};
#pragma unroll 8
    for (int kk = 0; kk < 64; ++kk) {
        float4 t0 = Ts4[kk*16 + cg*2];
        float4 t1 = Ts4[kk*16 + cg*2 + 1];
        float tv[8] = {t0.x,t0.y,t0.z,t0.w,t1.x,t1.y,t1.z,t1.w};
#pragma unroll
        for (int i = 0; i < 4; ++i) {
            float qv = qs[w][(rg*4+i)*65 + kk];
#pragma unroll
            for (int j = 0; j < 8; ++j) acc[i][j] += qv*tv[j];
        }
    }
#pragma unroll
    for (int i = 0; i < 4; ++i) {
        float dv = dinvs[w][rg*4 + i];
        long o = (rowbase + rg*4 + i)*64 + cg*8;
        *(float4*)(out + o)     = make_float4(acc[i][0]*dv, acc[i][1]*dv, acc[i][2]*dv, acc[i][3]*dv);
        *(float4*)(out + o + 4) = make_float4(acc[i][4]*dv, acc[i][5]*dv, acc[i][6]*dv, acc[i][7]*dv);
    }
}

extern "C" void kernel_launch(void* const* d_in, const int* in_sizes, int n_in,
                              void* d_out, int out_size, void* d_ws, size_t ws_size,
                              hipStream_t stream) {
    (void)in_sizes; (void)n_in; (void)out_size; (void)ws_size;
    const float* q = (const float*)d_in[0];
    const float* k = (const float*)d_in[1];
    const float* v = (const float*)d_in[2];
    const float* P = (const float*)d_in[3];
    float* out = (float*)d_out;
    float* ws  = (float*)d_ws;

    float* G  = ws + OFF_G;
    float* S  = ws + OFF_S;
    float* T  = ws + OFF_T;
    float* gs = ws + OFF_GS;
    float* pg = ws + OFF_PG;

    hipMemsetAsync(S, 0, (size_t)64*4096*sizeof(float), stream);
    kA_gram<<<64, 64, 0, stream>>>(P, G);
    // kg is materialized into d_out (exactly [B,H,N,64] floats); kernel D reads
    // only its own rows' kg before overwriting them with the final output.
    kB<<<dim3(16, 64), 256, 0, stream>>>(k, v, G, out, S, gs);
    kC<<<64, 256, 0, stream>>>(G, S, T, gs, pg);
    kD<<<dim3(32, 64), 256, 0, stream>>>(q, out, T, pg, out);
}